// Round 2
// baseline (564.977 us; speedup 1.0000x reference)
//
#include <hip/hip_runtime.h>
#include <stdint.h>
#include <math.h>

// WriteUnit fused — round 2: split-bf16 (hi+lo) x3 MFMA GEMMs.
// B=8192, T=12, D=512.
//  wconv   : Wc/Wl/Wg fp32 -> bf16 hi/lo planes (ws)
//  K1 gemm : selfControl = contControl @ Wc^T + bc   (MFMA, fp32-accurate)
//  K2 attn : logits->softmax->selfSmry, emitted as bf16 hi/lo planes
//  K3 gemm : newMemory (3 K-segs over Wl) + z (Wg), fused gating epilogue
// ws: selfControl 16MB + smry planes 16MB + weight planes 5MB = 37MB.

#define NB 8192
#define NT 12
#define ND 512

typedef short  bf16x8 __attribute__((ext_vector_type(8)));
typedef float  f32x4  __attribute__((ext_vector_type(4)));

__device__ __forceinline__ unsigned short f2bf(float x) {
    uint32_t u = __float_as_uint(x);
    uint32_t r = u + 0x7FFFu + ((u >> 16) & 1u);   // round-to-nearest-even
    return (unsigned short)(r >> 16);
}
__device__ __forceinline__ float bf2f(unsigned short h) {
    return __uint_as_float(((uint32_t)h) << 16);
}

// ---------------- weight split kernel ----------------
__global__ __launch_bounds__(256)
void wconv_kernel(const float* __restrict__ W, short* __restrict__ H,
                  short* __restrict__ L, int n4)
{
    int i = blockIdx.x * blockDim.x + threadIdx.x;
    if (i >= n4) return;
    float4 v = reinterpret_cast<const float4*>(W)[i];
    float xs[4] = {v.x, v.y, v.z, v.w};
    short4 hv, lv;
    short hh[4], ll[4];
#pragma unroll
    for (int j = 0; j < 4; ++j) {
        unsigned short h = f2bf(xs[j]);
        unsigned short l = f2bf(xs[j] - bf2f(h));
        hh[j] = (short)h; ll[j] = (short)l;
    }
    hv.x = hh[0]; hv.y = hh[1]; hv.z = hh[2]; hv.w = hh[3];
    lv.x = ll[0]; lv.y = ll[1]; lv.z = ll[2]; lv.w = ll[3];
    reinterpret_cast<short4*>(H)[i] = hv;
    reinterpret_cast<short4*>(L)[i] = lv;
}

// ---------------- GEMM core ----------------
// Tile 128(M) x 128(N), BK=32, 512 threads = 8 waves (2 wave-rows x 4 wave-cols),
// per-wave 64x32 via 4x2 frags of mfma_f32_16x16x32_bf16, x3 split terms.
// LDS tiles [2 bufs][128 rows][32 k] bf16, chunk-XOR swizzle c^=(row>>1)&3.

template<bool AF32>
__device__ __forceinline__ void run_seg(
    const float* __restrict__ Af,                       // AF32: fp32 A rows (stride ND)
    const short* __restrict__ Aph, const short* __restrict__ Apl,  // !AF32 planes
    const short* __restrict__ Wph, const short* __restrict__ Wpl,  // weight planes (block base)
    int sW,                                             // weight k-stride
    short* __restrict__ AhT, short* __restrict__ AlT,
    short* __restrict__ WhT, short* __restrict__ WlT,
    f32x4 (&acc)[4][2],
    const int soff, const int sr, const int sk,
    const int abase, const int wbase)
{
    float4 fa0, fa1;
    bf16x8 pah, pal, pwh, pwl;

    auto do_load = [&](int kt) {
        const int k = kt * 32 + sk;
        if constexpr (AF32) {
            fa0 = *reinterpret_cast<const float4*>(Af + (size_t)sr * ND + k);
            fa1 = *reinterpret_cast<const float4*>(Af + (size_t)sr * ND + k + 4);
        } else {
            pah = *reinterpret_cast<const bf16x8*>(Aph + (size_t)sr * ND + k);
            pal = *reinterpret_cast<const bf16x8*>(Apl + (size_t)sr * ND + k);
        }
        pwh = *reinterpret_cast<const bf16x8*>(Wph + (size_t)sr * sW + k);
        pwl = *reinterpret_cast<const bf16x8*>(Wpl + (size_t)sr * sW + k);
    };
    auto do_write = [&](int buf) {
        const int o = buf * 4096 + soff;
        if constexpr (AF32) {
            float xs[8] = {fa0.x, fa0.y, fa0.z, fa0.w, fa1.x, fa1.y, fa1.z, fa1.w};
            bf16x8 hv, lv;
#pragma unroll
            for (int j = 0; j < 8; ++j) {
                unsigned short h = f2bf(xs[j]);
                unsigned short l = f2bf(xs[j] - bf2f(h));
                hv[j] = (short)h; lv[j] = (short)l;
            }
            *reinterpret_cast<bf16x8*>(AhT + o) = hv;
            *reinterpret_cast<bf16x8*>(AlT + o) = lv;
        } else {
            *reinterpret_cast<bf16x8*>(AhT + o) = pah;
            *reinterpret_cast<bf16x8*>(AlT + o) = pal;
        }
        *reinterpret_cast<bf16x8*>(WhT + o) = pwh;
        *reinterpret_cast<bf16x8*>(WlT + o) = pwl;
    };

    do_load(0);
    do_write(0);
    __syncthreads();
    int cur = 0;
    for (int kt = 0; kt < 16; ++kt) {
        const bool pf = (kt + 1 < 16);
        if (pf) do_load(kt + 1);            // in flight during compute
        const int cb = cur * 4096;
        bf16x8 ah[4], al[4], wh[2], wl[2];
#pragma unroll
        for (int i = 0; i < 4; ++i) {
            ah[i] = *reinterpret_cast<const bf16x8*>(AhT + cb + abase + i * 512);
            al[i] = *reinterpret_cast<const bf16x8*>(AlT + cb + abase + i * 512);
        }
#pragma unroll
        for (int j = 0; j < 2; ++j) {
            wh[j] = *reinterpret_cast<const bf16x8*>(WhT + cb + wbase + j * 512);
            wl[j] = *reinterpret_cast<const bf16x8*>(WlT + cb + wbase + j * 512);
        }
#pragma unroll
        for (int i = 0; i < 4; ++i)
#pragma unroll
            for (int j = 0; j < 2; ++j) {
                acc[i][j] = __builtin_amdgcn_mfma_f32_16x16x32_bf16(ah[i], wh[j], acc[i][j], 0, 0, 0);
                acc[i][j] = __builtin_amdgcn_mfma_f32_16x16x32_bf16(ah[i], wl[j], acc[i][j], 0, 0, 0);
                acc[i][j] = __builtin_amdgcn_mfma_f32_16x16x32_bf16(al[i], wh[j], acc[i][j], 0, 0, 0);
            }
        if (pf) do_write(cur ^ 1);
        __syncthreads();
        cur ^= 1;
    }
}

#define GEMM_SETUP                                                         \
    const int t = threadIdx.x;                                             \
    const int bm = blockIdx.x, bn = blockIdx.y;                            \
    const int sr = t >> 2, scn = t & 3, sk = scn * 8;                      \
    const int soff = sr * 32 + (scn ^ ((sr >> 1) & 3)) * 8;                \
    const int w = t >> 6, wr = w >> 2, wc = w & 3;                         \
    const int lane = t & 63, fr = lane & 15, q = lane >> 4;                \
    const int rq = (q ^ ((fr >> 1) & 3)) * 8;                              \
    const int abase = (wr * 64 + fr) * 32 + rq;                            \
    const int wbase = (wc * 32 + fr) * 32 + rq;

// K1: selfControl = contControl @ Wc^T + bc
__global__ __launch_bounds__(512, 2)
void gemm_selfcontrol(const float* __restrict__ cc,
                      const short* __restrict__ wch, const short* __restrict__ wcl,
                      const float* __restrict__ bc,
                      float* __restrict__ sc_out)
{
    __shared__ __align__(16) short AhT[2 * 4096], AlT[2 * 4096];
    __shared__ __align__(16) short WhT[2 * 4096], WlT[2 * 4096];
    GEMM_SETUP
    f32x4 acc[4][2];
    const f32x4 zz = {0.f, 0.f, 0.f, 0.f};
#pragma unroll
    for (int i = 0; i < 4; ++i) { acc[i][0] = zz; acc[i][1] = zz; }

    run_seg<true>(cc + (size_t)bm * 128 * ND, nullptr, nullptr,
                  wch + (size_t)(bn * 128) * ND, wcl + (size_t)(bn * 128) * ND, ND,
                  AhT, AlT, WhT, WlT, acc, soff, sr, sk, abase, wbase);

    const int c0 = bn * 128 + wc * 32 + fr;
    const float bc0 = bc[c0], bc1 = bc[c0 + 16];
#pragma unroll
    for (int i = 0; i < 4; ++i) {
        const int r = bm * 128 + wr * 64 + i * 16 + q * 4;
#pragma unroll
        for (int ri = 0; ri < 4; ++ri) {
            sc_out[(size_t)(r + ri) * ND + c0]      = acc[i][0][ri] + bc0;
            sc_out[(size_t)(r + ri) * ND + c0 + 16] = acc[i][1][ri] + bc1;
        }
    }
}

// K3: newMemory + gate + combine
__global__ __launch_bounds__(512, 2)
void gemm_write(const float* __restrict__ memory, const float* __restrict__ info,
                const float* __restrict__ ctrl,
                const short* __restrict__ sh, const short* __restrict__ sl,
                const short* __restrict__ wlh, const short* __restrict__ wll,
                const short* __restrict__ wgh, const short* __restrict__ wgl,
                const float* __restrict__ bl_, const float* __restrict__ bg_,
                float* __restrict__ out)
{
    __shared__ __align__(16) short AhT[2 * 4096], AlT[2 * 4096];
    __shared__ __align__(16) short WhT[2 * 4096], WlT[2 * 4096];
    GEMM_SETUP
    f32x4 accN[4][2], accZ[4][2];
    const f32x4 zz = {0.f, 0.f, 0.f, 0.f};
#pragma unroll
    for (int i = 0; i < 4; ++i) {
        accN[i][0] = zz; accN[i][1] = zz;
        accZ[i][0] = zz; accZ[i][1] = zz;
    }

    const size_t ar = (size_t)bm * 128 * ND;
    const short* wlh_b = wlh + (size_t)(bn * 128) * 1536;
    const short* wll_b = wll + (size_t)(bn * 128) * 1536;

    run_seg<true >(memory + ar, nullptr, nullptr, wlh_b,        wll_b,        1536,
                   AhT, AlT, WhT, WlT, accN, soff, sr, sk, abase, wbase);
    run_seg<true >(info + ar,   nullptr, nullptr, wlh_b + 512,  wll_b + 512,  1536,
                   AhT, AlT, WhT, WlT, accN, soff, sr, sk, abase, wbase);
    run_seg<false>(nullptr, sh + ar, sl + ar,     wlh_b + 1024, wll_b + 1024, 1536,
                   AhT, AlT, WhT, WlT, accN, soff, sr, sk, abase, wbase);
    run_seg<true >(ctrl + ar,   nullptr, nullptr,
                   wgh + (size_t)(bn * 128) * ND, wgl + (size_t)(bn * 128) * ND, ND,
                   AhT, AlT, WhT, WlT, accZ, soff, sr, sk, abase, wbase);

    const int c0 = bn * 128 + wc * 32 + fr;
    const float blv[2] = {bl_[c0], bl_[c0 + 16]};
    const float bgv[2] = {bg_[c0], bg_[c0 + 16]};
#pragma unroll
    for (int i = 0; i < 4; ++i) {
        const int r = bm * 128 + wr * 64 + i * 16 + q * 4;
#pragma unroll
        for (int ri = 0; ri < 4; ++ri) {
#pragma unroll
            for (int j = 0; j < 2; ++j) {
                const int col = c0 + j * 16;
                const size_t idx = (size_t)(r + ri) * ND + col;
                const float nm = accN[i][j][ri] + blv[j];
                const float zl = accZ[i][j][ri] + bgv[j];
                const float z  = 1.f / (1.f + expf(-zl));
                const float m  = memory[idx];
                out[idx] = (nm - m) * z + m;
            }
        }
    }
}

// ---------------- attention ----------------
__global__ __launch_bounds__(256)
void attn_kernel(const float* __restrict__ allControls,
                 const float* __restrict__ allMemories,
                 const float* __restrict__ selfControl,
                 const float* __restrict__ Wa,
                 const float* __restrict__ ba,
                 short* __restrict__ sh, short* __restrict__ sl)
{
    __shared__ float red[4][NT];
    __shared__ float lg[NT];
    const int b = blockIdx.x;
    const int t = threadIdx.x;
    const int lane = t & 63, wv = t >> 6;

    const float2 sc = ((const float2*)(selfControl + (size_t)b * ND))[t];
    const float2 wa = ((const float2*)Wa)[t];
    const float swx = sc.x * wa.x, swy = sc.y * wa.y;

    const float2* ac2 = (const float2*)(allControls + (size_t)b * NT * ND);
    float part[NT];
#pragma unroll
    for (int tt = 0; tt < NT; ++tt) {
        float2 v = ac2[tt * 256 + t];
        part[tt] = fmaf(v.x, swx, v.y * swy);
    }
#pragma unroll
    for (int tt = 0; tt < NT; ++tt) {
        float v = part[tt];
#pragma unroll
        for (int m = 1; m < 64; m <<= 1) v += __shfl_xor(v, m, 64);
        if (lane == 0) red[wv][tt] = v;
    }
    __syncthreads();
    if (t < NT) lg[t] = red[0][t] + red[1][t] + red[2][t] + red[3][t] + ba[0];
    __syncthreads();

    float l[NT], mx = -1e30f;
#pragma unroll
    for (int tt = 0; tt < NT; ++tt) { l[tt] = lg[tt]; mx = fmaxf(mx, l[tt]); }
    float e[NT], s = 0.f;
#pragma unroll
    for (int tt = 0; tt < NT; ++tt) { e[tt] = expf(l[tt] - mx); s += e[tt]; }
    const float inv = 1.f / s;

    const float2* am2 = (const float2*)(allMemories + (size_t)b * NT * ND);
    float ax = 0.f, ay = 0.f;
#pragma unroll
    for (int tt = 0; tt < NT; ++tt) {
        float2 v = am2[tt * 256 + t];
        const float wgt = e[tt] * inv;
        ax = fmaf(wgt, v.x, ax);
        ay = fmaf(wgt, v.y, ay);
    }
    // emit split-bf16 planes
    unsigned short hx = f2bf(ax); unsigned short lx = f2bf(ax - bf2f(hx));
    unsigned short hy = f2bf(ay); unsigned short ly = f2bf(ay - bf2f(hy));
    short2 hv; hv.x = (short)hx; hv.y = (short)hy;
    short2 lv; lv.x = (short)lx; lv.y = (short)ly;
    reinterpret_cast<short2*>(sh + (size_t)b * ND)[t] = hv;
    reinterpret_cast<short2*>(sl + (size_t)b * ND)[t] = lv;
}

extern "C" void kernel_launch(void* const* d_in, const int* in_sizes, int n_in,
                              void* d_out, int out_size, void* d_ws, size_t ws_size,
                              hipStream_t stream) {
    const float* memory      = (const float*)d_in[0];
    const float* info        = (const float*)d_in[1];
    const float* control     = (const float*)d_in[2];
    const float* contControl = (const float*)d_in[3];
    const float* allControls = (const float*)d_in[4];
    const float* allMemories = (const float*)d_in[5];
    const float* Wc          = (const float*)d_in[6];
    const float* bc          = (const float*)d_in[7];
    // Wa = d_in[8], ba = d_in[9]
    const float* Wl          = (const float*)d_in[10];
    const float* bl          = (const float*)d_in[11];
    const float* Wg          = (const float*)d_in[12];
    const float* bg          = (const float*)d_in[13];
    float* out = (float*)d_out;

    char* wsb = (char*)d_ws;
    float* selfControl = (float*)wsb;                            // 16 MB
    short* sh  = (short*)(wsb + (size_t)16 * 1024 * 1024);       // 8 MB
    short* sl  = sh  + (size_t)NB * ND;                          // 8 MB
    short* wch = sl  + (size_t)NB * ND;
    short* wcl = wch + 512 * 512;
    short* wlh = wcl + 512 * 512;
    short* wll = wlh + 512 * 1536;
    short* wgh = wll + 512 * 1536;
    short* wgl = wgh + 512 * 512;                                 // end ~37 MB

    wconv_kernel<<<(512 * 512 / 4 + 255) / 256, 256, 0, stream>>>(Wc, wch, wcl, 512 * 512 / 4);
    wconv_kernel<<<(512 * 1536 / 4 + 255) / 256, 256, 0, stream>>>(Wl, wlh, wll, 512 * 1536 / 4);
    wconv_kernel<<<(512 * 512 / 4 + 255) / 256, 256, 0, stream>>>(Wg, wgh, wgl, 512 * 512 / 4);

    dim3 ggrid(NB / 128, ND / 128);   // 64 x 4
    gemm_selfcontrol<<<ggrid, 512, 0, stream>>>(contControl, wch, wcl,
                                                (const float*)d_in[7], selfControl);
    attn_kernel<<<NB, 256, 0, stream>>>(allControls, allMemories, selfControl,
                                        (const float*)d_in[8], (const float*)d_in[9],
                                        sh, sl);
    gemm_write<<<ggrid, 512, 0, stream>>>(memory, info, control, sh, sl,
                                          wlh, wll, wgh, wgl, bl, bg, out);
}

// Round 3
// 562.571 us; speedup vs baseline: 1.0043x; 1.0043x over previous
//
#include <hip/hip_runtime.h>
#include <stdint.h>
#include <math.h>

// WriteUnit fused — round 3: wave-per-row barrier-free attention + Wa fold.
// B=8192, T=12, D=512.
//  wconv_all : Wc/Wl/Wg fp32 -> bf16 hi/lo planes (one launch)
//  K1 gemm   : v = (contControl @ Wc^T + bc) * Wa   (split-bf16 x3 MFMA)
//  K2 attn   : logits->softmax->selfSmry, wave-per-row, no barriers
//  K3 gemm   : newMemory (3 K-segs over Wl) + z (Wg), fused gating epilogue
// ws: v 16MB + smry planes 16MB + weight planes 5MB = 37MB.

#define NB 8192
#define NT 12
#define ND 512

typedef short  bf16x8 __attribute__((ext_vector_type(8)));
typedef float  f32x4  __attribute__((ext_vector_type(4)));

__device__ __forceinline__ unsigned short f2bf(float x) {
    uint32_t u = __float_as_uint(x);
    uint32_t r = u + 0x7FFFu + ((u >> 16) & 1u);   // round-to-nearest-even
    return (unsigned short)(r >> 16);
}
__device__ __forceinline__ float bf2f(unsigned short h) {
    return __uint_as_float(((uint32_t)h) << 16);
}

// ---------------- weight split kernel (all 3 weights, one launch) ----------------
// float4 counts: Wc 65536, Wl 196608, Wg 65536  -> total 327680
__global__ __launch_bounds__(256)
void wconv_all(const float* __restrict__ Wc, const float* __restrict__ Wl,
               const float* __restrict__ Wg,
               short* __restrict__ wch, short* __restrict__ wcl,
               short* __restrict__ wlh, short* __restrict__ wll,
               short* __restrict__ wgh, short* __restrict__ wgl)
{
    int i = blockIdx.x * 256 + threadIdx.x;
    const float* src; short* H; short* L; int j;
    if (i < 65536)        { src = Wc; H = wch; L = wcl; j = i; }
    else if (i < 262144)  { src = Wl; H = wlh; L = wll; j = i - 65536; }
    else                  { src = Wg; H = wgh; L = wgl; j = i - 262144; }
    float4 v = reinterpret_cast<const float4*>(src)[j];
    float xs[4] = {v.x, v.y, v.z, v.w};
    short4 hv, lv;
    short hh[4], ll[4];
#pragma unroll
    for (int k = 0; k < 4; ++k) {
        unsigned short h = f2bf(xs[k]);
        unsigned short l = f2bf(xs[k] - bf2f(h));
        hh[k] = (short)h; ll[k] = (short)l;
    }
    hv.x = hh[0]; hv.y = hh[1]; hv.z = hh[2]; hv.w = hh[3];
    lv.x = ll[0]; lv.y = ll[1]; lv.z = ll[2]; lv.w = ll[3];
    reinterpret_cast<short4*>(H)[j] = hv;
    reinterpret_cast<short4*>(L)[j] = lv;
}

// ---------------- GEMM core (unchanged from round 2 — validated) ----------------
// Tile 128(M) x 128(N), BK=32, 512 threads = 8 waves (2x4), per-wave 64x32 via
// 4x2 frags of mfma_f32_16x16x32_bf16, x3 split terms. Double-buffered LDS,
// chunk-XOR swizzle.

template<bool AF32>
__device__ __forceinline__ void run_seg(
    const float* __restrict__ Af,
    const short* __restrict__ Aph, const short* __restrict__ Apl,
    const short* __restrict__ Wph, const short* __restrict__ Wpl,
    int sW,
    short* __restrict__ AhT, short* __restrict__ AlT,
    short* __restrict__ WhT, short* __restrict__ WlT,
    f32x4 (&acc)[4][2],
    const int soff, const int sr, const int sk,
    const int abase, const int wbase)
{
    float4 fa0, fa1;
    bf16x8 pah, pal, pwh, pwl;

    auto do_load = [&](int kt) {
        const int k = kt * 32 + sk;
        if constexpr (AF32) {
            fa0 = *reinterpret_cast<const float4*>(Af + (size_t)sr * ND + k);
            fa1 = *reinterpret_cast<const float4*>(Af + (size_t)sr * ND + k + 4);
        } else {
            pah = *reinterpret_cast<const bf16x8*>(Aph + (size_t)sr * ND + k);
            pal = *reinterpret_cast<const bf16x8*>(Apl + (size_t)sr * ND + k);
        }
        pwh = *reinterpret_cast<const bf16x8*>(Wph + (size_t)sr * sW + k);
        pwl = *reinterpret_cast<const bf16x8*>(Wpl + (size_t)sr * sW + k);
    };
    auto do_write = [&](int buf) {
        const int o = buf * 4096 + soff;
        if constexpr (AF32) {
            float xs[8] = {fa0.x, fa0.y, fa0.z, fa0.w, fa1.x, fa1.y, fa1.z, fa1.w};
            bf16x8 hv, lv;
#pragma unroll
            for (int j = 0; j < 8; ++j) {
                unsigned short h = f2bf(xs[j]);
                unsigned short l = f2bf(xs[j] - bf2f(h));
                hv[j] = (short)h; lv[j] = (short)l;
            }
            *reinterpret_cast<bf16x8*>(AhT + o) = hv;
            *reinterpret_cast<bf16x8*>(AlT + o) = lv;
        } else {
            *reinterpret_cast<bf16x8*>(AhT + o) = pah;
            *reinterpret_cast<bf16x8*>(AlT + o) = pal;
        }
        *reinterpret_cast<bf16x8*>(WhT + o) = pwh;
        *reinterpret_cast<bf16x8*>(WlT + o) = pwl;
    };

    do_load(0);
    do_write(0);
    __syncthreads();
    int cur = 0;
    for (int kt = 0; kt < 16; ++kt) {
        const bool pf = (kt + 1 < 16);
        if (pf) do_load(kt + 1);
        const int cb = cur * 4096;
        bf16x8 ah[4], al[4], wh[2], wl[2];
#pragma unroll
        for (int i = 0; i < 4; ++i) {
            ah[i] = *reinterpret_cast<const bf16x8*>(AhT + cb + abase + i * 512);
            al[i] = *reinterpret_cast<const bf16x8*>(AlT + cb + abase + i * 512);
        }
#pragma unroll
        for (int j = 0; j < 2; ++j) {
            wh[j] = *reinterpret_cast<const bf16x8*>(WhT + cb + wbase + j * 512);
            wl[j] = *reinterpret_cast<const bf16x8*>(WlT + cb + wbase + j * 512);
        }
#pragma unroll
        for (int i = 0; i < 4; ++i)
#pragma unroll
            for (int j = 0; j < 2; ++j) {
                acc[i][j] = __builtin_amdgcn_mfma_f32_16x16x32_bf16(ah[i], wh[j], acc[i][j], 0, 0, 0);
                acc[i][j] = __builtin_amdgcn_mfma_f32_16x16x32_bf16(ah[i], wl[j], acc[i][j], 0, 0, 0);
                acc[i][j] = __builtin_amdgcn_mfma_f32_16x16x32_bf16(al[i], wh[j], acc[i][j], 0, 0, 0);
            }
        if (pf) do_write(cur ^ 1);
        __syncthreads();
        cur ^= 1;
    }
}

#define GEMM_SETUP                                                         \
    const int t = threadIdx.x;                                             \
    const int bm = blockIdx.x, bn = blockIdx.y;                            \
    const int sr = t >> 2, scn = t & 3, sk = scn * 8;                      \
    const int soff = sr * 32 + (scn ^ ((sr >> 1) & 3)) * 8;                \
    const int w = t >> 6, wr = w >> 2, wc = w & 3;                         \
    const int lane = t & 63, fr = lane & 15, q = lane >> 4;                \
    const int rq = (q ^ ((fr >> 1) & 3)) * 8;                              \
    const int abase = (wr * 64 + fr) * 32 + rq;                            \
    const int wbase = (wc * 32 + fr) * 32 + rq;

// K1: v = (contControl @ Wc^T + bc) * Wa   (Wa folded; ba dropped — cancels in softmax)
__global__ __launch_bounds__(512, 2)
void gemm_selfcontrol(const float* __restrict__ cc,
                      const short* __restrict__ wch, const short* __restrict__ wcl,
                      const float* __restrict__ bc, const float* __restrict__ Wa,
                      float* __restrict__ v_out)
{
    __shared__ __align__(16) short AhT[2 * 4096], AlT[2 * 4096];
    __shared__ __align__(16) short WhT[2 * 4096], WlT[2 * 4096];
    GEMM_SETUP
    f32x4 acc[4][2];
    const f32x4 zz = {0.f, 0.f, 0.f, 0.f};
#pragma unroll
    for (int i = 0; i < 4; ++i) { acc[i][0] = zz; acc[i][1] = zz; }

    run_seg<true>(cc + (size_t)bm * 128 * ND, nullptr, nullptr,
                  wch + (size_t)(bn * 128) * ND, wcl + (size_t)(bn * 128) * ND, ND,
                  AhT, AlT, WhT, WlT, acc, soff, sr, sk, abase, wbase);

    const int c0 = bn * 128 + wc * 32 + fr;
    const float bc0 = bc[c0], bc1 = bc[c0 + 16];
    const float wa0 = Wa[c0], wa1 = Wa[c0 + 16];
#pragma unroll
    for (int i = 0; i < 4; ++i) {
        const int r = bm * 128 + wr * 64 + i * 16 + q * 4;
#pragma unroll
        for (int ri = 0; ri < 4; ++ri) {
            v_out[(size_t)(r + ri) * ND + c0]      = (acc[i][0][ri] + bc0) * wa0;
            v_out[(size_t)(r + ri) * ND + c0 + 16] = (acc[i][1][ri] + bc1) * wa1;
        }
    }
}

// K3: newMemory + gate + combine (unchanged)
__global__ __launch_bounds__(512, 2)
void gemm_write(const float* __restrict__ memory, const float* __restrict__ info,
                const float* __restrict__ ctrl,
                const short* __restrict__ sh, const short* __restrict__ sl,
                const short* __restrict__ wlh, const short* __restrict__ wll,
                const short* __restrict__ wgh, const short* __restrict__ wgl,
                const float* __restrict__ bl_, const float* __restrict__ bg_,
                float* __restrict__ out)
{
    __shared__ __align__(16) short AhT[2 * 4096], AlT[2 * 4096];
    __shared__ __align__(16) short WhT[2 * 4096], WlT[2 * 4096];
    GEMM_SETUP
    f32x4 accN[4][2], accZ[4][2];
    const f32x4 zz = {0.f, 0.f, 0.f, 0.f};
#pragma unroll
    for (int i = 0; i < 4; ++i) {
        accN[i][0] = zz; accN[i][1] = zz;
        accZ[i][0] = zz; accZ[i][1] = zz;
    }

    const size_t ar = (size_t)bm * 128 * ND;
    const short* wlh_b = wlh + (size_t)(bn * 128) * 1536;
    const short* wll_b = wll + (size_t)(bn * 128) * 1536;

    run_seg<true >(memory + ar, nullptr, nullptr, wlh_b,        wll_b,        1536,
                   AhT, AlT, WhT, WlT, accN, soff, sr, sk, abase, wbase);
    run_seg<true >(info + ar,   nullptr, nullptr, wlh_b + 512,  wll_b + 512,  1536,
                   AhT, AlT, WhT, WlT, accN, soff, sr, sk, abase, wbase);
    run_seg<false>(nullptr, sh + ar, sl + ar,     wlh_b + 1024, wll_b + 1024, 1536,
                   AhT, AlT, WhT, WlT, accN, soff, sr, sk, abase, wbase);
    run_seg<true >(ctrl + ar,   nullptr, nullptr,
                   wgh + (size_t)(bn * 128) * ND, wgl + (size_t)(bn * 128) * ND, ND,
                   AhT, AlT, WhT, WlT, accZ, soff, sr, sk, abase, wbase);

    const int c0 = bn * 128 + wc * 32 + fr;
    const float blv[2] = {bl_[c0], bl_[c0 + 16]};
    const float bgv[2] = {bg_[c0], bg_[c0 + 16]};
#pragma unroll
    for (int i = 0; i < 4; ++i) {
        const int r = bm * 128 + wr * 64 + i * 16 + q * 4;
#pragma unroll
        for (int ri = 0; ri < 4; ++ri) {
#pragma unroll
            for (int j = 0; j < 2; ++j) {
                const int col = c0 + j * 16;
                const size_t idx = (size_t)(r + ri) * ND + col;
                const float nm = accN[i][j][ri] + blv[j];
                const float zl = accZ[i][j][ri] + bgv[j];
                const float z  = 1.f / (1.f + expf(-zl));
                const float m  = memory[idx];
                out[idx] = (nm - m) * z + m;
            }
        }
    }
}

// ---------------- attention: one wave per batch row, no barriers ----------------
__global__ __launch_bounds__(256)
void attn_wave(const float* __restrict__ allControls,
               const float* __restrict__ allMemories,
               const float* __restrict__ v,
               short* __restrict__ sh, short* __restrict__ sl)
{
    const int gtid = blockIdx.x * 256 + threadIdx.x;
    const int b    = gtid >> 6;            // one wave per row
    const int lane = gtid & 63;
    const int e0   = lane * 8;             // this lane's 8 elements

    const float4* vp = reinterpret_cast<const float4*>(v + (size_t)b * ND + e0);
    const float4 v0 = vp[0], v1 = vp[1];

    const float* acb = allControls + (size_t)b * NT * ND + e0;
    float part[NT];
#pragma unroll
    for (int tt = 0; tt < NT; ++tt) {
        const float4 c0 = *reinterpret_cast<const float4*>(acb + tt * ND);
        const float4 c1 = *reinterpret_cast<const float4*>(acb + tt * ND + 4);
        float p = c0.x * v0.x;
        p = fmaf(c0.y, v0.y, p); p = fmaf(c0.z, v0.z, p); p = fmaf(c0.w, v0.w, p);
        p = fmaf(c1.x, v1.x, p); p = fmaf(c1.y, v1.y, p);
        p = fmaf(c1.z, v1.z, p); p = fmaf(c1.w, v1.w, p);
        part[tt] = p;
    }
    // 12 independent 6-step butterflies (ILP, no LDS, no barrier)
#pragma unroll
    for (int tt = 0; tt < NT; ++tt) {
        float p = part[tt];
#pragma unroll
        for (int m = 1; m < 64; m <<= 1) p += __shfl_xor(p, m);
        part[tt] = p;
    }
    float mx = part[0];
#pragma unroll
    for (int tt = 1; tt < NT; ++tt) mx = fmaxf(mx, part[tt]);
    float e[NT], s = 0.f;
#pragma unroll
    for (int tt = 0; tt < NT; ++tt) { e[tt] = expf(part[tt] - mx); s += e[tt]; }
    const float inv = 1.f / s;

    const float* amb = allMemories + (size_t)b * NT * ND + e0;
    float o[8] = {0.f, 0.f, 0.f, 0.f, 0.f, 0.f, 0.f, 0.f};
#pragma unroll
    for (int tt = 0; tt < NT; ++tt) {
        const float w = e[tt] * inv;
        const float4 m0 = *reinterpret_cast<const float4*>(amb + tt * ND);
        const float4 m1 = *reinterpret_cast<const float4*>(amb + tt * ND + 4);
        o[0] = fmaf(w, m0.x, o[0]); o[1] = fmaf(w, m0.y, o[1]);
        o[2] = fmaf(w, m0.z, o[2]); o[3] = fmaf(w, m0.w, o[3]);
        o[4] = fmaf(w, m1.x, o[4]); o[5] = fmaf(w, m1.y, o[5]);
        o[6] = fmaf(w, m1.z, o[6]); o[7] = fmaf(w, m1.w, o[7]);
    }
    bf16x8 hv, lv;
#pragma unroll
    for (int j = 0; j < 8; ++j) {
        unsigned short h = f2bf(o[j]);
        unsigned short l = f2bf(o[j] - bf2f(h));
        hv[j] = (short)h; lv[j] = (short)l;
    }
    *reinterpret_cast<bf16x8*>(sh + (size_t)b * ND + e0) = hv;
    *reinterpret_cast<bf16x8*>(sl + (size_t)b * ND + e0) = lv;
}

extern "C" void kernel_launch(void* const* d_in, const int* in_sizes, int n_in,
                              void* d_out, int out_size, void* d_ws, size_t ws_size,
                              hipStream_t stream) {
    const float* memory      = (const float*)d_in[0];
    const float* info        = (const float*)d_in[1];
    const float* control     = (const float*)d_in[2];
    const float* contControl = (const float*)d_in[3];
    const float* allControls = (const float*)d_in[4];
    const float* allMemories = (const float*)d_in[5];
    const float* Wc          = (const float*)d_in[6];
    const float* bc          = (const float*)d_in[7];
    const float* Wa          = (const float*)d_in[8];
    // ba = d_in[9] — cancels in softmax, unused
    const float* Wl          = (const float*)d_in[10];
    const float* bl          = (const float*)d_in[11];
    const float* Wg          = (const float*)d_in[12];
    const float* bg          = (const float*)d_in[13];
    float* out = (float*)d_out;

    char* wsb = (char*)d_ws;
    float* v   = (float*)wsb;                                    // 16 MB
    short* sh  = (short*)(wsb + (size_t)16 * 1024 * 1024);       // 8 MB
    short* sl  = sh  + (size_t)NB * ND;                          // 8 MB
    short* wch = sl  + (size_t)NB * ND;
    short* wcl = wch + 512 * 512;
    short* wlh = wcl + 512 * 512;
    short* wll = wlh + 512 * 1536;
    short* wgh = wll + 512 * 1536;
    short* wgl = wgh + 512 * 512;                                 // end ~37 MB

    wconv_all<<<1280, 256, 0, stream>>>(Wc, Wl, Wg, wch, wcl, wlh, wll, wgh, wgl);

    dim3 ggrid(NB / 128, ND / 128);   // 64 x 4
    gemm_selfcontrol<<<ggrid, 512, 0, stream>>>(contControl, wch, wcl, bc, Wa, v);
    attn_wave<<<NB * 64 / 256, 256, 0, stream>>>(allControls, allMemories, v, sh, sl);
    gemm_write<<<ggrid, 512, 0, stream>>>(memory, info, control, sh, sl,
                                          wlh, wll, wgh, wgl, bl, bg, out);
}